// Round 14
// baseline (531.762 us; speedup 1.0000x reference)
//
// R23: R13 base + clean f16-MFMA gemm for layers 1-3 (separate kernel, copy-only staging,
// 2-term W-split). Layer 0 keeps verified f32/bf16 3-term path, now single-path.
#include <hip/hip_runtime.h>
#include <hip/hip_bf16.h>
#include <math.h>

#define PSPLIT 8
#define BSH 8                  // bucket = dst >> BSH  (256 dsts/bucket)
#define NBMAX 512              // max buckets (N <= 131072, matches 17-bit src pack)
#define CHUNK 8192             // edges per bscat block (32KB LDS staging)
#define AST 40                 // LDS row stride in shorts (80B: 16B-aligned, 2-way banks max)

typedef float v4f __attribute__((ext_vector_type(4)));
typedef float v2f __attribute__((ext_vector_type(2)));
typedef unsigned int v4u __attribute__((ext_vector_type(4)));
typedef unsigned int v2u __attribute__((ext_vector_type(2)));
typedef __attribute__((ext_vector_type(8))) short bf8;
typedef _Float16 h8 __attribute__((ext_vector_type(8)));
typedef __attribute__((ext_vector_type(4))) float f4;
typedef unsigned short u16;
typedef unsigned int u32;

static inline size_t align_up(size_t x, size_t a){ return (x + a - 1) & ~(a - 1); }

__device__ inline void bf_split(float v, u16& hi, u16& lo){
  __hip_bfloat16 h = __float2bfloat16(v);
  float hf = __bfloat162float(h);
  __hip_bfloat16 l = __float2bfloat16(v - hf);
  hi = *(u16*)&h; lo = *(u16*)&l;
}

// fused fp16->f32 convert + accumulate: a += (float)lo16(p) / hi16(p).
__device__ inline void fmixlo(float& a, u32 p){
  asm("v_fma_mix_f32 %0, %1, 1.0, %0 op_sel:[0,0,0] op_sel_hi:[1,0,0]" : "+v"(a) : "v"(p));
}
__device__ inline void fmixhi(float& a, u32 p){
  asm("v_fma_mix_f32 %0, %1, 1.0, %0 op_sel:[1,0,0] op_sel_hi:[1,0,0]" : "+v"(a) : "v"(p));
}

__device__ inline float f16lo(u32 p){ u16 q = (u16)p; return (float)*(_Float16*)&q; }
__device__ inline float f16hi(u32 p){ u16 q = (u16)(p >> 16); return (float)*(_Float16*)&q; }

// fast tanh: 1 - 2/(exp2(2*log2e*x)+1).  v_exp+v_rcp, ~4e-7 abs err, inf/NaN-safe.
__device__ inline float tanh_fast(float x){
  float u = __builtin_amdgcn_exp2f(x * 2.8853900817779268f);
  float q = __builtin_amdgcn_rcpf(u + 1.0f);
  return fmaf(-2.0f, q, 1.0f);
}

// ---------------- graph prep: bucketed CSR build ----------------
// R17 multisplit (verified R5): LDS-staged, coalesced full-line copy-out.

__global__ __launch_bounds__(256) void k_bhist(const int* __restrict__ col, int* __restrict__ bcnt,
                                               int E, int NB,
                                               const int* __restrict__ batch, int* __restrict__ gstart,
                                               int n, int G){
  extern __shared__ int lh[];
  for (int i = threadIdx.x; i < NB; i += 256) lh[i] = 0;
  __syncthreads();
  for (int e = blockIdx.x * 256 + threadIdx.x; e < E; e += gridDim.x * 256)
    atomicAdd(&lh[col[e] >> BSH], 1);
  __syncthreads();
  for (int i = threadIdx.x; i < NB; i += 256){
    int v = lh[i];
    if (v) atomicAdd(&bcnt[i], v);
  }
  // fused gstart
  for (int i = blockIdx.x * 256 + threadIdx.x; i < n; i += gridDim.x * 256){
    int cb = batch[i];
    if (i == 0){ for (int g = 0; g <= cb; ++g) gstart[g] = 0; }
    else { int pb = batch[i - 1]; for (int g = pb + 1; g <= cb; ++g) gstart[g] = i; }
    if (i == n - 1){ for (int g = cb + 1; g <= G; ++g) gstart[g] = n; }
  }
}

__global__ void k_bscan(const int* __restrict__ bcnt, int* __restrict__ boff, int NB, int E,
                        int* __restrict__ rp, int N){
  __shared__ int sd[256];
  int t = threadIdx.x;
  int c[16]; int s = 0;
  const int PT = (NB + 255) / 256;   // <= 2 at BSH=8
  for (int j = 0; j < PT; ++j){ int i = t * PT + j; c[j] = (i < NB) ? bcnt[i] : 0; s += c[j]; }
  sd[t] = s; __syncthreads();
  for (int off = 1; off < 256; off <<= 1){
    int v = sd[t];
    if (t >= off) v += sd[t - off];
    __syncthreads(); sd[t] = v; __syncthreads();
  }
  int run = sd[t] - s;
  for (int j = 0; j < PT; ++j){ int i = t * PT + j; if (i < NB) boff[i] = run; run += c[j]; }
  if (t == 255){ boff[NB] = run; rp[N] = E; }
}

// LDS-staged multisplit scatter (verified R5): coalesced full-line copy-out.
__global__ __launch_bounds__(256) void k_bscat(const int* __restrict__ ei, const int* __restrict__ boff,
                                               int* __restrict__ bfill, unsigned* __restrict__ tmp,
                                               int E, int NB){
  __shared__ int lh[NBMAX], loff[NBMAX], gb[NBMAX], lfil[NBMAX];
  __shared__ int sd[256];
  __shared__ int sumA;
  __shared__ u32 stg[CHUNK];
  int t = threadIdx.x;
  const int* col = ei + E;
  int c0 = blockIdx.x * CHUNK;
  int c1 = c0 + CHUNK; if (c1 > E) c1 = E;

  for (int i = t; i < NBMAX; i += 256){ lh[i] = 0; lfil[i] = 0; }
  __syncthreads();
  // pass 1: local histogram
  for (int e = c0 + t; e < c1; e += 256)
    atomicAdd(&lh[col[e] >> BSH], 1);
  __syncthreads();
  // exclusive scan of lh[0..511] -> loff (two 256-cell tiers)
  sd[t] = lh[t]; __syncthreads();
  for (int off = 1; off < 256; off <<= 1){
    int v = sd[t];
    if (t >= off) v += sd[t - off];
    __syncthreads(); sd[t] = v; __syncthreads();
  }
  loff[t] = sd[t] - lh[t];
  if (t == 255) sumA = sd[255];
  __syncthreads();
  int lb = lh[256 + t];
  sd[t] = lb; __syncthreads();
  for (int off = 1; off < 256; off <<= 1){
    int v = sd[t];
    if (t >= off) v += sd[t - off];
    __syncthreads(); sd[t] = v; __syncthreads();
  }
  loff[256 + t] = sumA + sd[t] - lb;
  // claim global ranges
  for (int i = t; i < NB; i += 256){
    int c = lh[i];
    gb[i] = c ? (boff[i] + atomicAdd(&bfill[i * 16], c)) : 0;
  }
  __syncthreads();
  // pass 2: rank + stage
  for (int e = c0 + t; e < c1; e += 256){
    int d = col[e], s = ei[e];
    int b = d >> BSH;
    int p = atomicAdd(&lfil[b], 1);
    stg[loff[b] + p] = (unsigned)s | ((unsigned)(d & 255) << 17);
  }
  __syncthreads();
  // copy-out: wave w handles buckets w, w+4, ... (coalesced per-bucket runs)
  int wv = t >> 6, lane = t & 63;
  for (int b = wv; b < NB; b += 4){
    int len = lh[b];
    if (!len) continue;
    int base = gb[b], lo = loff[b];
    for (int j = lane; j < len; j += 64) tmp[base + j] = stg[lo + j];
  }
}

// per-bucket 256-bin counting sort (verified R5).
__global__ __launch_bounds__(256) void k_bfin(const unsigned* __restrict__ tmp, const int* __restrict__ boff,
                                              int* __restrict__ ssrc, int* __restrict__ rp,
                                              float* __restrict__ dinv, int N){
  int b = blockIdx.x;
  int d0 = b << BSH;
  int lim = N - d0; if (lim > 256) lim = 256;
  __shared__ int dcnt[256], dexc[256], lfill[256];
  int t = threadIdx.x;
  dcnt[t] = 0; lfill[t] = 0;
  __syncthreads();
  int lo = boff[b], hi = boff[b + 1];
  for (int i = lo + t; i < hi; i += 256) atomicAdd(&dcnt[tmp[i] >> 17], 1);
  __syncthreads();
  int cme = dcnt[t];
  dexc[t] = cme; __syncthreads();
  for (int off = 1; off < 256; off <<= 1){
    int v = dexc[t];
    if (t >= off) v += dexc[t - off];
    __syncthreads(); dexc[t] = v; __syncthreads();
  }
  int excl = dexc[t] - cme;
  __syncthreads();
  dexc[t] = excl;
  if (t < lim){
    int d = d0 + t;
    rp[d] = lo + excl;
    double dd = (double)(cme + 1);               // +1 self-loop
    dinv[d] = (float)(1.0 / sqrt(dd));
  }
  __syncthreads();
  for (int i = lo + t; i < hi; i += 256){
    unsigned r = tmp[i];
    int l = r >> 17;
    int pos = dexc[l] + atomicAdd(&lfill[l], 1);
    ssrc[lo + pos] = (int)(r & 0x1FFFFu);
  }
}

// ---------------- W conversion: f32 [k][n] -> TRANSPOSED [l][n][k] planes ----------------
// bf16 hi/lo (layer-0 path) and fp16 hi/residual (layers 1-3 f16-MFMA path, rel ~2^-22).

__global__ __launch_bounds__(256) void k_cvtw(const float* __restrict__ w0, const float* __restrict__ w1,
                                              const float* __restrict__ w2, const float* __restrict__ w3,
                                              u16* __restrict__ wth, u16* __restrict__ wtl,
                                              u16* __restrict__ fth, u16* __restrict__ ftl){
  int id = blockIdx.x * 256 + threadIdx.x;
  if (id >= 4 * 16384) return;
  int l = id >> 14, rem = id & 16383, k = rem >> 7, nn = rem & 127;
  const float* Wsrc = (l == 0) ? w0 : (l == 1) ? w1 : (l == 2) ? w2 : w3;
  float v = Wsrc[k * 128 + nn];
  int idx = (l << 14) + nn * 128 + k;
  u16 hi, lo; bf_split(v, hi, lo);
  wth[idx] = hi;
  wtl[idx] = lo;
  _Float16 fh = (_Float16)v;
  float fr = v - (float)fh;
  _Float16 fl = (_Float16)fr;
  fth[idx] = *(u16*)&fh;
  ftl[idx] = *(u16*)&fl;
}

// ---------------- GEMM layer 0 (MFMA): C = (A_f32 @ W) * dinv ----------------
// R7-verified structure, single path (f32 input, split-bf16 3-term MFMA), R22 A-prefetch.

__global__ __launch_bounds__(256, 4) void k_gemm(const float* __restrict__ A,
                                                 const u16* __restrict__ wth, const u16* __restrict__ wtl,
                                                 const float* __restrict__ dinv,
                                                 u16* __restrict__ C, int n){
  __shared__ u16 Ah[128 * AST], Al[128 * AST], Wh[128 * AST], Wl[128 * AST];
  int t = threadIdx.x;
  int r0 = blockIdx.x * 128;
  int wv = t >> 6, lane = t & 63;
  int q = lane >> 4, ln = lane & 15;

  int srow = t >> 1;               // 0..127
  int shalf = (t & 1) * 16;        // k-offset within 32-chunk
  int grow = r0 + srow; if (grow > n - 1) grow = n - 1;
  const float* ga = A + (size_t)grow * 128 + shalf;
  const u16* gwh = wth + srow * 128 + shalf;
  const u16* gwl = wtl + srow * 128 + shalf;

  f4 acc[2][8];
  #pragma unroll
  for (int mt = 0; mt < 2; ++mt)
    #pragma unroll
    for (int nt = 0; nt < 8; ++nt) acc[mt][nt] = (f4)(0.f);

  float4 fA0, fA1, fA2, fA3;
  auto LDA = [&](int c){
    const float4* gp = (const float4*)(ga + c * 32);
    fA0 = gp[0]; fA1 = gp[1]; fA2 = gp[2]; fA3 = gp[3];
  };
  LDA(0);

  for (int c = 0; c < 4; ++c){
    __syncthreads();
    {
      u16* ah = &Ah[srow * AST + shalf];
      u16* al = &Al[srow * AST + shalf];
      float4 v_[4] = {fA0, fA1, fA2, fA3};
      #pragma unroll
      for (int i = 0; i < 4; ++i){
        float4 v = v_[i];
        u16 h0,h1,h2,h3,l0,l1,l2,l3;
        bf_split(v.x, h0, l0); bf_split(v.y, h1, l1);
        bf_split(v.z, h2, l2); bf_split(v.w, h3, l3);
        ushort4 hv = {h0,h1,h2,h3}, lv = {l0,l1,l2,l3};
        *(ushort4*)&ah[i * 4] = hv;
        *(ushort4*)&al[i * 4] = lv;
      }
      const u16* ph = gwh + c * 32;
      const u16* pl = gwl + c * 32;
      bf8 h0 = *(const bf8*)ph, h1 = *(const bf8*)(ph + 8);
      bf8 l0 = *(const bf8*)pl, l1 = *(const bf8*)(pl + 8);
      *(bf8*)&Wh[srow * AST + shalf] = h0; *(bf8*)&Wh[srow * AST + shalf + 8] = h1;
      *(bf8*)&Wl[srow * AST + shalf] = l0; *(bf8*)&Wl[srow * AST + shalf + 8] = l1;
    }
    if (c < 3) LDA(c + 1);
    __syncthreads();

    bf8 afh[2], afl[2];
    #pragma unroll
    for (int mt = 0; mt < 2; ++mt){
      int row = wv * 32 + mt * 16 + ln;
      afh[mt] = *(const bf8*)&Ah[row * AST + q * 8];
      afl[mt] = *(const bf8*)&Al[row * AST + q * 8];
    }
    #pragma unroll
    for (int nt = 0; nt < 8; ++nt){
      int wn = nt * 16 + ln;
      bf8 wfh = *(const bf8*)&Wh[wn * AST + q * 8];
      bf8 wfl = *(const bf8*)&Wl[wn * AST + q * 8];
      #pragma unroll
      for (int mt = 0; mt < 2; ++mt){
        acc[mt][nt] = __builtin_amdgcn_mfma_f32_16x16x32_bf16(afh[mt], wfh, acc[mt][nt], 0, 0, 0);
        acc[mt][nt] = __builtin_amdgcn_mfma_f32_16x16x32_bf16(afl[mt], wfh, acc[mt][nt], 0, 0, 0);
        acc[mt][nt] = __builtin_amdgcn_mfma_f32_16x16x32_bf16(afh[mt], wfl, acc[mt][nt], 0, 0, 0);
      }
    }
  }

  #pragma unroll
  for (int mt = 0; mt < 2; ++mt){
    int base_m = r0 + wv * 32 + mt * 16 + q * 4;
    float dv[4];
    #pragma unroll
    for (int reg = 0; reg < 4; ++reg){
      int row = base_m + reg;
      dv[reg] = (row < n) ? dinv[row] : 0.f;
    }
    #pragma unroll
    for (int nt = 0; nt < 8; ++nt){
      #pragma unroll
      for (int reg = 0; reg < 4; ++reg){
        int row = base_m + reg;
        if (row < n){
          _Float16 hv = (_Float16)(acc[mt][nt][reg] * dv[reg]);
          C[(size_t)row * 128 + nt * 16 + ln] = *(u16*)&hv;
        }
      }
    }
  }
}

// ---------------- GEMM layers 1-3 (f16 MFMA): C = (A_fp16 @ (Wh+Wl)) * dinv ----------------
// R23: A is EXACT fp16 (tanh output) -> A-staging is a pure 32B copy (zero conversion VALU);
// W = fp16 hi + fp16 residual (combined rel err ~2^-22); 2 MFMA terms (vs 3). Separate
// kernel so layer-0's bf16 path doesn't inflate register pressure (R6's confound).
// f16 frag layout correctness was verified by R6's passing run (absmax 7.6e-6).

__global__ __launch_bounds__(256, 4) void k_gemmf16(const u32* __restrict__ A,
                                                    const u16* __restrict__ fth, const u16* __restrict__ ftl,
                                                    const float* __restrict__ dinv,
                                                    u16* __restrict__ C, int n){
  __shared__ u16 Af[128 * AST], Wh[128 * AST], Wl[128 * AST];
  int t = threadIdx.x;
  int r0 = blockIdx.x * 128;
  int wv = t >> 6, lane = t & 63;
  int q = lane >> 4, ln = lane & 15;

  int srow = t >> 1;               // 0..127
  int shalf = (t & 1) * 16;        // k-offset within 32-chunk
  int grow = r0 + srow; if (grow > n - 1) grow = n - 1;
  const u32* gap = A + (size_t)grow * 64 + (shalf >> 1);
  const u16* gwh = fth + srow * 128 + shalf;
  const u16* gwl = ftl + srow * 128 + shalf;

  f4 acc[2][8];
  #pragma unroll
  for (int mt = 0; mt < 2; ++mt)
    #pragma unroll
    for (int nt = 0; nt < 8; ++nt) acc[mt][nt] = (f4)(0.f);

  bf8 pA0, pA1;                    // prefetched A chunk (16 fp16 = 32B, bit-copied)
  auto LDA = [&](int c){
    const bf8* gp = (const bf8*)(gap + c * 16);
    pA0 = gp[0]; pA1 = gp[1];
  };
  LDA(0);

  for (int c = 0; c < 4; ++c){
    __syncthreads();
    // stage A: pure copy (fp16 bits straight into fragment layout)
    *(bf8*)&Af[srow * AST + shalf] = pA0;
    *(bf8*)&Af[srow * AST + shalf + 8] = pA1;
    // stage W hi/lo
    {
      const u16* ph = gwh + c * 32;
      const u16* pl = gwl + c * 32;
      bf8 h0 = *(const bf8*)ph, h1 = *(const bf8*)(ph + 8);
      bf8 l0 = *(const bf8*)pl, l1 = *(const bf8*)(pl + 8);
      *(bf8*)&Wh[srow * AST + shalf] = h0; *(bf8*)&Wh[srow * AST + shalf + 8] = h1;
      *(bf8*)&Wl[srow * AST + shalf] = l0; *(bf8*)&Wl[srow * AST + shalf + 8] = l1;
    }
    if (c < 3) LDA(c + 1);          // next-chunk A loads land under MFMA
    __syncthreads();

    h8 af[2];
    #pragma unroll
    for (int mt = 0; mt < 2; ++mt){
      int row = wv * 32 + mt * 16 + ln;
      af[mt] = *(const h8*)&Af[row * AST + q * 8];
    }
    #pragma unroll
    for (int nt = 0; nt < 8; ++nt){
      int wn = nt * 16 + ln;
      h8 wfh = *(const h8*)&Wh[wn * AST + q * 8];
      h8 wfl = *(const h8*)&Wl[wn * AST + q * 8];
      #pragma unroll
      for (int mt = 0; mt < 2; ++mt){
        acc[mt][nt] = __builtin_amdgcn_mfma_f32_16x16x32_f16(af[mt], wfh, acc[mt][nt], 0, 0, 0);
        acc[mt][nt] = __builtin_amdgcn_mfma_f32_16x16x32_f16(af[mt], wfl, acc[mt][nt], 0, 0, 0);
      }
    }
  }

  #pragma unroll
  for (int mt = 0; mt < 2; ++mt){
    int base_m = r0 + wv * 32 + mt * 16 + q * 4;
    float dv[4];
    #pragma unroll
    for (int reg = 0; reg < 4; ++reg){
      int row = base_m + reg;
      dv[reg] = (row < n) ? dinv[row] : 0.f;
    }
    #pragma unroll
    for (int nt = 0; nt < 8; ++nt){
      #pragma unroll
      for (int reg = 0; reg < 4; ++reg){
        int row = base_m + reg;
        if (row < n){
          _Float16 hv = (_Float16)(acc[mt][nt][reg] * dv[reg]);
          C[(size_t)row * 128 + nt * 16 + ln] = *(u16*)&hv;
        }
      }
    }
  }
}

// ---------------- aggregate: h_out = tanh(dinv[d]*(sum hw'[src] + hw'[d]) + b) ----------------
// R14 structure (verified best, 59us at the ~3.9 TB/s L2-fill wall, FETCH 192MB ~ 8% over
// the 177MB 8-XCD analytic floor): ONE WAVE PER NODE, 256B fp16 row gather, lane = u32 =
// 2 features. node wave-uniform (readfirstlane) -> scalar rp/ssrc; 16 gathers in flight.

__global__ __launch_bounds__(256) void k_agg(const u16* __restrict__ hwp, const int* __restrict__ rp,
                                             const int* __restrict__ ssrc,
                                             const float* __restrict__ dinv, const float* __restrict__ bias,
                                             u32* __restrict__ hout, int n){
  int node = blockIdx.x * 4 + (threadIdx.x >> 6);
  node = __builtin_amdgcn_readfirstlane(node);
  if (node >= n) return;
  int lane = threadIdx.x & 63;
  const u32* hw32 = (const u32*)hwp;          // row = 64 u32 = 256B

  int e0 = rp[node], e1 = rp[node + 1];
  float a0 = 0.f, a1 = 0.f;
  int e = e0;
  while (e + 16 <= e1){
    u32 p[16];
    #pragma unroll
    for (int i = 0; i < 16; ++i){
      int s = ssrc[e + i];
      p[i] = hw32[(size_t)s * 64 + lane];
    }
    #pragma unroll
    for (int i = 0; i < 16; ++i){ fmixlo(a0, p[i]); fmixhi(a1, p[i]); }
    e += 16;
  }
  while (e + 4 <= e1){
    u32 p[4];
    #pragma unroll
    for (int i = 0; i < 4; ++i){
      int s = ssrc[e + i];
      p[i] = hw32[(size_t)s * 64 + lane];
    }
    #pragma unroll
    for (int i = 0; i < 4; ++i){ fmixlo(a0, p[i]); fmixhi(a1, p[i]); }
    e += 4;
  }
  while (e < e1){
    int s = ssrc[e];
    u32 p = hw32[(size_t)s * 64 + lane];
    fmixlo(a0, p); fmixhi(a1, p);
    ++e;
  }
  // self term (already * dinv[node])
  {
    u32 p = hw32[(size_t)node * 64 + lane];
    fmixlo(a0, p); fmixhi(a1, p);
  }
  float di = dinv[node];
  v2f bv = *(const v2f*)(bias + lane * 2);
  float r0 = tanh_fast(fmaf(a0, di, bv.x));
  float r1 = tanh_fast(fmaf(a1, di, bv.y));
  _Float16 f0 = (_Float16)r0, f1 = (_Float16)r1;
  u32 pv = ((u32)(*(u16*)&f1) << 16) | (u32)(*(u16*)&f0);
  __builtin_nontemporal_store(pv, hout + (size_t)node * 64 + lane);
}

// ---------------- pool: stage 1 partial max/sum over fp16-packed h ----------------

__global__ __launch_bounds__(256) void k_pool1(const u32* __restrict__ h, const int* __restrict__ gstart,
                                               float* __restrict__ pmx, float* __restrict__ psm){
  int g = blockIdx.x >> 3, s = blockIdx.x & (PSPLIT - 1);
  int t = threadIdx.x;
  int fq = t & 31;             // feature quad (4 features = 2 u32)
  int rw = t >> 5;             // row slot 0..7
  int i0 = gstart[g], i1 = gstart[g + 1];
  int len = i1 - i0;
  int chunk = (len + PSPLIT - 1) / PSPLIT;
  int a = i0 + s * chunk;
  int b = a + chunk; if (b > i1) b = i1;

  const v2u* hv = (const v2u*)h;   // 32 v2u per row
  v4f mx = (v4f)(-INFINITY), sm = (v4f)(0.f);
  for (int i = a + rw; i < b; i += 8){
    v2u p = hv[(size_t)i * 32 + fq];
    float x0 = f16lo(p.x), x1 = f16hi(p.x), x2 = f16lo(p.y), x3 = f16hi(p.y);
    mx.x = fmaxf(mx.x, x0); mx.y = fmaxf(mx.y, x1);
    mx.z = fmaxf(mx.z, x2); mx.w = fmaxf(mx.w, x3);
    sm.x += x0; sm.y += x1; sm.z += x2; sm.w += x3;
  }
  __shared__ v4f smx[8][32], ssm[8][32];
  smx[rw][fq] = mx; ssm[rw][fq] = sm;
  __syncthreads();
  if (rw == 0){
    #pragma unroll
    for (int r2 = 1; r2 < 8; ++r2){
      v4f m2 = smx[r2][fq], s2 = ssm[r2][fq];
      mx.x = fmaxf(mx.x, m2.x); mx.y = fmaxf(mx.y, m2.y);
      mx.z = fmaxf(mx.z, m2.z); mx.w = fmaxf(mx.w, m2.w);
      sm += s2;
    }
    ((v4f*)pmx)[(size_t)blockIdx.x * 32 + fq] = mx;
    ((v4f*)psm)[(size_t)blockIdx.x * 32 + fq] = sm;
  }
}

__global__ __launch_bounds__(128) void k_head(const float* __restrict__ pmx, const float* __restrict__ psm,
                                              const int* __restrict__ gstart,
                                              const float* __restrict__ Wl, const float* __restrict__ bl,
                                              float* __restrict__ out){
  int g = blockIdx.x, f = threadIdx.x;
  float mx = -INFINITY, sm = 0.f;
  #pragma unroll
  for (int s = 0; s < PSPLIT; ++s){
    mx = fmaxf(mx, pmx[((size_t)g * PSPLIT + s) * 128 + f]);
    sm += psm[((size_t)g * PSPLIT + s) * 128 + f];
  }
  int cnt = gstart[g + 1] - gstart[g];
  if (cnt <= 0) mx = 0.f;
  float mn = sm / (float)(cnt > 0 ? cnt : 1);
  float contrib = mx * Wl[f] + mn * Wl[128 + f];
  for (int o = 32; o > 0; o >>= 1) contrib += __shfl_down(contrib, o);
  __shared__ float sred[2];
  if ((f & 63) == 0) sred[f >> 6] = contrib;
  __syncthreads();
  if (f == 0) out[g] = sred[0] + sred[1] + bl[0];
}

// ---------------- launch ----------------

extern "C" void kernel_launch(void* const* d_in, const int* in_sizes, int n_in,
                              void* d_out, int out_size, void* d_ws, size_t ws_size,
                              hipStream_t stream){
  const float* x     = (const float*)d_in[0];
  const int*   ei    = (const int*)d_in[1];
  const int*   batch = (const int*)d_in[2];
  const float* W[4]  = {(const float*)d_in[3], (const float*)d_in[5], (const float*)d_in[7], (const float*)d_in[9]};
  const float* B[4]  = {(const float*)d_in[4], (const float*)d_in[6], (const float*)d_in[8], (const float*)d_in[10]};
  const float* Wl    = (const float*)d_in[11];
  const float* bl    = (const float*)d_in[12];
  float* out = (float*)d_out;

  int N = in_sizes[0] / 128;
  int E = in_sizes[1] / 2;
  int G = out_size;
  int NB = (N + 255) >> BSH;

  char* ws = (char*)d_ws;
  size_t off = 0;
  auto alloc = [&](size_t bytes) -> void* {
    void* p = ws + off; off = align_up(off + bytes, 256); return p;
  };
  float* dinv  = (float*)alloc((size_t)N * 4);
  int*   rp    = (int*)  alloc((size_t)(N + 1) * 4);
  int*   bcnt  = (int*)  alloc((size_t)(NB + 1) * 4);
  int*   boff  = (int*)  alloc((size_t)(NB + 1) * 4);
  int*   bfill = (int*)  alloc((size_t)NB * 16 * 4);   // 64B-padded claim counters
  int*   gst   = (int*)  alloc((size_t)(G + 1) * 4);
  int*   ssrc  = (int*)  alloc((size_t)E * 4);
  u16*   wth   = (u16*)  alloc((size_t)4 * 16384 * 2);
  u16*   wtl   = (u16*)  alloc((size_t)4 * 16384 * 2);
  u16*   fth   = (u16*)  alloc((size_t)4 * 16384 * 2);
  u16*   ftl   = (u16*)  alloc((size_t)4 * 16384 * 2);
  float* pmx   = (float*)alloc((size_t)G * PSPLIT * 128 * 4);
  float* psm   = (float*)alloc((size_t)G * PSPLIT * 128 * 4);
  u16*   hw    = (u16*)  alloc((size_t)N * 128 * 2);   // fp16 message buffer, row-major [N][128]
  u32*   h     = (u32*)  alloc((size_t)N * 64 * 4);    // fp16-packed activations, row-major
  unsigned* tmp = (unsigned*)hw;   // alias: tmp (E*4=6.4MB) dead before first gemm writes hw (25.6MB)

  hipMemsetAsync(bcnt, 0, (size_t)(NB + 1) * 4, stream);
  hipMemsetAsync(bfill, 0, (size_t)NB * 16 * 4, stream);

  k_cvtw <<<256, 256, 0, stream>>>(W[0], W[1], W[2], W[3], wth, wtl, fth, ftl);
  k_bhist<<<128, 256, NB * 4, stream>>>(ei + E, bcnt, E, NB, batch, gst, N, G);
  k_bscan<<<1, 256, 0, stream>>>(bcnt, boff, NB, E, rp, N);
  k_bscat<<<(E + CHUNK - 1) / CHUNK, 256, 0, stream>>>(ei, boff, bfill, tmp, E, NB);
  k_bfin <<<NB, 256, 0, stream>>>(tmp, boff, ssrc, rp, dinv, N);

  int gemmG = (N + 127) / 128;
  int aggG  = (N + 3) / 4;                 // one wave per node, 4 waves/block
  for (int l = 0; l < 4; ++l){
    if (l == 0)
      k_gemm<<<gemmG, 256, 0, stream>>>(x, wth, wtl, dinv, hw, N);
    else
      k_gemmf16<<<gemmG, 256, 0, stream>>>((const u32*)h, fth + (l << 14), ftl + (l << 14), dinv, hw, N);
    k_agg<<<aggG, 256, 0, stream>>>(hw, rp, ssrc, dinv, B[l], h, N);
  }
  k_pool1<<<G * PSPLIT, 256, 0, stream>>>(h, gst, pmx, psm);
  k_head <<<G, 128, 0, stream>>>(pmx, psm, gst, Wl, bl, out);
}